// Round 2
// baseline (273.736 us; speedup 1.0000x reference)
//
#include <hip/hip_runtime.h>

#define TOKENS 8192
#define EXPERTS 64
#define HIDDEN 4096
#define SPLIT 8
#define KSEG (HIDDEN / SPLIT)   // 512 k per block
#define CHUNK 128               // k staged per LDS pass

// ---------------------------------------------------------------------------
// Kernel A: transpose weight [64][4096] -> wT [4096][64], LDS-tiled so both
// global read and write are coalesced.
// ---------------------------------------------------------------------------
__global__ void transpose_w_kernel(const float* __restrict__ w,
                                   float* __restrict__ wT) {
    __shared__ float tile[64][65];
    const int tid = threadIdx.x;           // 256 threads
    const int kb = blockIdx.x * 64;        // 64 k per block, 64 blocks
    // read: 4 expert-rows per pass, 64 consecutive k per row (coalesced)
#pragma unroll
    for (int p = 0; p < 16; ++p) {
        const int e = p * 4 + (tid >> 6);
        const int kk = tid & 63;
        tile[e][kk] = w[(size_t)e * HIDDEN + kb + kk];
    }
    __syncthreads();
    // write: 4 k-rows per pass, 64 consecutive experts per row (coalesced)
#pragma unroll
    for (int q = 0; q < 16; ++q) {
        const int kr = q * 4 + (tid >> 6);
        const int ee = tid & 63;
        wT[(size_t)(kb + kr) * 64 + ee] = tile[ee][kr];
    }
}

// ---------------------------------------------------------------------------
// Kernel B: partial logits. Grid = 128 token-groups x SPLIT k-segments,
// block = 256 threads (4 waves). lane = token; acc[64] = one VGPR per expert.
// Each wave computes 32 of each 128-k staged chunk; weights are wave-uniform
// (scalar loads from wT), x comes from a transposed padded LDS tile.
// Epilogue: cross-wave LDS reduction, one partial write per block.
// ---------------------------------------------------------------------------
__global__ __launch_bounds__(256, 4)
void logits_partial_kernel(const float* __restrict__ x,
                           const float* __restrict__ wT,
                           float* __restrict__ part) {
    __shared__ float smem[CHUNK * 65];     // 33.3 KB: xs during compute, red after
    const int tid = threadIdx.x;
    const int wid = tid >> 6;
    const int lane = tid & 63;
    const int g = blockIdx.x / SPLIT;      // token group (0..127)
    const int s = blockIdx.x % SPLIT;      // k segment (0..7)
    const int t0 = g * 64;
    const int k0 = s * KSEG;

    float acc[EXPERTS];
#pragma unroll
    for (int e = 0; e < EXPERTS; ++e) acc[e] = 0.0f;

    const int rowb = tid >> 5;             // 0..7
    const int kk4 = (tid & 31) * 4;

    for (int c = 0; c < KSEG / CHUNK; ++c) {   // 4 chunks
        __syncthreads();
        // stage x[t0..t0+63][k0+c*128 .. +128) -> smem[k][token] (pad 65)
        // global: 32 lanes x float4 = 512B contiguous per row-slice
#pragma unroll
        for (int p = 0; p < 8; ++p) {
            const int row = p * 8 + rowb;
            const float4 v = *reinterpret_cast<const float4*>(
                x + (size_t)(t0 + row) * HIDDEN + k0 + c * CHUNK + kk4);
            smem[(kk4 + 0) * 65 + row] = v.x;
            smem[(kk4 + 1) * 65 + row] = v.y;
            smem[(kk4 + 2) * 65 + row] = v.z;
            smem[(kk4 + 3) * 65 + row] = v.w;
        }
        __syncthreads();
        // compute: wave wid owns k-local [wid*32, wid*32+32)
        const float* __restrict__ wbase = wT + (size_t)(k0 + c * CHUNK) * 64;
#pragma unroll 4
        for (int kk = 0; kk < 32; ++kk) {
            const int kl = wid * 32 + kk;
            const float xv = smem[kl * 65 + lane];
            const float* __restrict__ wrow = wbase + kl * 64;
#pragma unroll
            for (int e = 0; e < EXPERTS; ++e) {
                acc[e] = fmaf(wrow[e], xv, acc[e]);
            }
        }
    }

    // cross-wave reduction: red[token][expert], stride 65 (conflict-free)
    float* red = smem;
    __syncthreads();
    if (wid == 0) {
#pragma unroll
        for (int e = 0; e < EXPERTS; ++e) red[lane * 65 + e] = acc[e];
    }
    __syncthreads();
#pragma unroll
    for (int w = 1; w < 4; ++w) {
        if (wid == w) {
#pragma unroll
            for (int e = 0; e < EXPERTS; ++e) red[lane * 65 + e] += acc[e];
        }
        __syncthreads();
    }

    // write partial: part[s][t0+t][e], coalesced float4 stores
    const int t = tid >> 2;
    const int e0 = (tid & 3) * 16;
    float* dst = part + ((size_t)s * TOKENS + t0 + t) * EXPERTS + e0;
#pragma unroll
    for (int j = 0; j < 16; j += 4) {
        float4 v;
        v.x = red[t * 65 + e0 + j + 0];
        v.y = red[t * 65 + e0 + j + 1];
        v.z = red[t * 65 + e0 + j + 2];
        v.w = red[t * 65 + e0 + j + 3];
        *reinterpret_cast<float4*>(dst + j) = v;
    }
}

// ---------------------------------------------------------------------------
// Kernel C: reduce partials -> softmax -> top-8 -> probs + routing map.
// One wave per token; lane = expert. Tie-break: lower index (lax.top_k).
// ---------------------------------------------------------------------------
__global__ void reduce_topk_kernel(const float* __restrict__ part,
                                   float* __restrict__ out) {
    const int wid = threadIdx.x >> 6;
    const int lane = threadIdx.x & 63;
    const int t = blockIdx.x * 4 + wid;

    float logit = 0.0f;
#pragma unroll
    for (int s = 0; s < SPLIT; ++s) {
        logit += part[((size_t)s * TOKENS + t) * EXPERTS + lane];
    }

    // softmax over the 64 lanes
    float m = logit;
#pragma unroll
    for (int off = 32; off >= 1; off >>= 1) m = fmaxf(m, __shfl_xor(m, off, 64));
    const float ex = __expf(logit - m);
    float sum = ex;
#pragma unroll
    for (int off = 32; off >= 1; off >>= 1) sum += __shfl_xor(sum, off, 64);
    const float score = ex / sum;

    // iterative top-8: argmax with (value desc, index asc) tie-break
    float v = score;
    bool sel = false;
#pragma unroll
    for (int it = 0; it < 8; ++it) {
        float bv = v;
        int bi = lane;
#pragma unroll
        for (int off = 32; off >= 1; off >>= 1) {
            const float ov = __shfl_xor(bv, off, 64);
            const int oi = __shfl_xor(bi, off, 64);
            if (ov > bv || (ov == bv && oi < bi)) { bv = ov; bi = oi; }
        }
        if (lane == bi) { sel = true; v = -1.0f; }  // scores are > 0
    }

    out[(size_t)t * EXPERTS + lane] = sel ? score : 0.0f;
    out[(size_t)TOKENS * EXPERTS + (size_t)t * EXPERTS + lane] = sel ? 1.0f : 0.0f;
}

// ---------------------------------------------------------------------------
extern "C" void kernel_launch(void* const* d_in, const int* in_sizes, int n_in,
                              void* d_out, int out_size, void* d_ws, size_t ws_size,
                              hipStream_t stream) {
    (void)in_sizes; (void)n_in; (void)out_size; (void)ws_size;
    const float* x = (const float*)d_in[0];       // [8192][4096] f32
    const float* w = (const float*)d_in[1];       // [64][4096] f32
    float* out = (float*)d_out;                   // probs [T][E] then map [T][E]

    float* wT = (float*)d_ws;                                     // 1 MB
    float* part = (float*)((char*)d_ws + (size_t)(1 << 20));      // 16 MB

    transpose_w_kernel<<<HIDDEN / 64, 256, 0, stream>>>(w, wT);
    logits_partial_kernel<<<(TOKENS / 64) * SPLIT, 256, 0, stream>>>(x, wT, part);
    reduce_topk_kernel<<<TOKENS / 4, 256, 0, stream>>>(part, out);
}

// Round 3
// 83.061 us; speedup vs baseline: 3.2956x; 3.2956x over previous
//
#include <hip/hip_runtime.h>

#define TOKENS 8192
#define EXPERTS 64
#define HIDDEN 4096
#define CHUNK 64                 // k staged per LDS pass
#define PAD 68                   // row stride in floats: 272B = 17*16B (float4-aligned, bank-clean)

// ---------------------------------------------------------------------------
// Kernel A: transpose weight [64][4096] -> wT [4096][64], LDS-tiled.
// ---------------------------------------------------------------------------
__global__ void transpose_w_kernel(const float* __restrict__ w,
                                   float* __restrict__ wT) {
    __shared__ float tile[64][65];
    const int tid = threadIdx.x;           // 256 threads
    const int kb = blockIdx.x * 64;        // 64 k per block, 64 blocks
#pragma unroll
    for (int p = 0; p < 16; ++p) {
        const int e = p * 4 + (tid >> 6);
        const int kk = tid & 63;
        tile[e][kk] = w[(size_t)e * HIDDEN + kb + kk];
    }
    __syncthreads();
#pragma unroll
    for (int q = 0; q < 16; ++q) {
        const int kr = q * 4 + (tid >> 6);
        const int ee = tid & 63;
        wT[(size_t)(kb + kr) * 64 + ee] = tile[ee][kr];
    }
}

// ---------------------------------------------------------------------------
// Kernel B: partial logits.
// Grid = 128 token-groups x split k-segments, block = 256 (4 waves).
// lane = token. Wave w owns experts [w*16, w*16+16) over the whole K-segment
// -> acc[16] per thread (register-resident). Expert base forced scalar via
// readfirstlane so weight loads become wave-uniform s_load.
// x staged row-major [token][k] with PAD=68 -> float4 staging stores and
// ds_read_b128 compute reads, both conflict-free.
// ---------------------------------------------------------------------------
__global__ __launch_bounds__(256, 6)
void logits_partial_kernel(const float* __restrict__ x,
                           const float* __restrict__ wT,
                           float* __restrict__ part,
                           int split, int kseg) {
    __shared__ float smem[64 * PAD];       // 17.4 KB
    const int tid = threadIdx.x;
    const int lane = tid & 63;
    const int e0 = __builtin_amdgcn_readfirstlane((tid >> 6) * 16);
    const int g = blockIdx.x / split;      // token group (0..127)
    const int s = blockIdx.x % split;      // k segment
    const int t0 = g * 64;
    const int k0 = s * kseg;

    float acc[16];
#pragma unroll
    for (int j = 0; j < 16; ++j) acc[j] = 0.0f;

    const int rowb = tid >> 4;             // 0..15
    const int kk4 = (tid & 15) * 4;        // float4 column within 64-k chunk

    for (int c = 0; c < kseg; c += CHUNK) {
        __syncthreads();
        // stage x[t0..t0+63][k0+c .. +64) -> smem[row][k] (row stride PAD)
#pragma unroll
        for (int p = 0; p < 4; ++p) {
            const int row = p * 16 + rowb;
            const float4 v = *reinterpret_cast<const float4*>(
                x + (size_t)(t0 + row) * HIDDEN + k0 + c + kk4);
            *reinterpret_cast<float4*>(&smem[row * PAD + kk4]) = v;
        }
        __syncthreads();

        const float* __restrict__ wbase = wT + (size_t)(k0 + c) * 64 + e0;
        for (int kk = 0; kk < CHUNK; kk += 4) {
            const float4 xv = *reinterpret_cast<const float4*>(
                &smem[lane * PAD + kk]);
            const float* __restrict__ wrow = wbase + (size_t)kk * 64;
#pragma unroll
            for (int j = 0; j < 16; ++j)
                acc[j] = fmaf(wrow[j], xv.x, acc[j]);
#pragma unroll
            for (int j = 0; j < 16; ++j)
                acc[j] = fmaf(wrow[64 + j], xv.y, acc[j]);
#pragma unroll
            for (int j = 0; j < 16; ++j)
                acc[j] = fmaf(wrow[128 + j], xv.z, acc[j]);
#pragma unroll
            for (int j = 0; j < 16; ++j)
                acc[j] = fmaf(wrow[192 + j], xv.w, acc[j]);
        }
    }

    // write partial: part[s][t0+lane][e0..e0+15], 4x float4 per lane
    float* dst = part + ((size_t)s * TOKENS + t0 + lane) * EXPERTS + e0;
#pragma unroll
    for (int j = 0; j < 16; j += 4) {
        float4 v = make_float4(acc[j], acc[j + 1], acc[j + 2], acc[j + 3]);
        *reinterpret_cast<float4*>(dst + j) = v;
    }
}

// ---------------------------------------------------------------------------
// Kernel C: reduce partials -> softmax -> top-8 -> probs + routing map.
// One wave per token; lane = expert. Tie-break: lower index (lax.top_k).
// ---------------------------------------------------------------------------
__global__ void reduce_topk_kernel(const float* __restrict__ part,
                                   float* __restrict__ out, int split) {
    const int wid = threadIdx.x >> 6;
    const int lane = threadIdx.x & 63;
    const int t = blockIdx.x * 4 + wid;

    float logit = 0.0f;
    for (int s = 0; s < split; ++s) {
        logit += part[((size_t)s * TOKENS + t) * EXPERTS + lane];
    }

    // softmax over the 64 lanes
    float m = logit;
#pragma unroll
    for (int off = 32; off >= 1; off >>= 1) m = fmaxf(m, __shfl_xor(m, off, 64));
    const float ex = __expf(logit - m);
    float sum = ex;
#pragma unroll
    for (int off = 32; off >= 1; off >>= 1) sum += __shfl_xor(sum, off, 64);
    const float score = ex / sum;

    // iterative top-8: argmax with (value desc, index asc) tie-break
    float v = score;
    bool sel = false;
#pragma unroll
    for (int it = 0; it < 8; ++it) {
        float bv = v;
        int bi = lane;
#pragma unroll
        for (int off = 32; off >= 1; off >>= 1) {
            const float ov = __shfl_xor(bv, off, 64);
            const int oi = __shfl_xor(bi, off, 64);
            if (ov > bv || (ov == bv && oi < bi)) { bv = ov; bi = oi; }
        }
        if (lane == bi) { sel = true; v = -1.0f; }  // scores are > 0
    }

    out[(size_t)t * EXPERTS + lane] = sel ? score : 0.0f;
    out[(size_t)TOKENS * EXPERTS + (size_t)t * EXPERTS + lane] = sel ? 1.0f : 0.0f;
}

// ---------------------------------------------------------------------------
extern "C" void kernel_launch(void* const* d_in, const int* in_sizes, int n_in,
                              void* d_out, int out_size, void* d_ws, size_t ws_size,
                              hipStream_t stream) {
    (void)in_sizes; (void)n_in; (void)out_size;
    const float* x = (const float*)d_in[0];       // [8192][4096] f32
    const float* w = (const float*)d_in[1];       // [64][4096] f32
    float* out = (float*)d_out;                   // probs [T][E] then map [T][E]

    float* wT = (float*)d_ws;                                     // 1 MB
    float* part = (float*)((char*)d_ws + (size_t)(1 << 20));

    // pick largest split whose partial buffer fits the workspace
    int split = 16;
    while (split > 1 &&
           (size_t)(1 << 20) + (size_t)split * TOKENS * EXPERTS * 4 > ws_size) {
        split >>= 1;
    }
    const int kseg = HIDDEN / split;

    transpose_w_kernel<<<HIDDEN / 64, 256, 0, stream>>>(w, wT);
    logits_partial_kernel<<<(TOKENS / 64) * split, 256, 0, stream>>>(x, wT, part,
                                                                     split, kseg);
    reduce_topk_kernel<<<TOKENS / 4, 256, 0, stream>>>(part, out, split);
}